// Round 6
// baseline (215.980 us; speedup 1.0000x reference)
//
#include <hip/hip_runtime.h>

#define N_IN   256
#define NCEN   2048
#define NOUT   128
#define BR     64
#define XP     264          // prologue-only padded X stride (shorts)
#define RTP    40           // wave-private R tile col stride (shorts): 80 B rows, 16B-aligned
#define LOG2E  1.4426950408889634f

typedef __bf16 bf16x8 __attribute__((ext_vector_type(8)));
typedef float  f32x4  __attribute__((ext_vector_type(4)));

__device__ __forceinline__ unsigned short f2bf(float f) {
  unsigned int u = __builtin_bit_cast(unsigned int, f);
  u += 0x7FFFu + ((u >> 16) & 1u);            // round-to-nearest-even
  return (unsigned short)(u >> 16);
}

__device__ __forceinline__ bf16x8 ldfrag(const unsigned short* p) {
  return __builtin_bit_cast(bf16x8, *reinterpret_cast<const uint4*>(p));
}

// ---------------- prep: fp32 -> bf16 for centers & W, |c|^2, -log2e*beta ----------
__global__ __launch_bounds__(256) void rbfn_prep(
    const float* __restrict__ centers, const float* __restrict__ W,
    const float* __restrict__ beta,
    unsigned short* __restrict__ cbw, unsigned short* __restrict__ wbw,
    float* __restrict__ csq, float* __restrict__ nb2)
{
  const int b = blockIdx.x;
  const int tid = threadIdx.x;
  if (b < 512) {                      // centers: 4 rows per block, 1 wave per row
    const int wave = tid >> 6, lane = tid & 63;
    const int row = b * 4 + wave;
    float4 v = reinterpret_cast<const float4*>(centers + row * N_IN)[lane];
    float ss = v.x * v.x + v.y * v.y + v.z * v.z + v.w * v.w;
    ushort4 pk = { f2bf(v.x), f2bf(v.y), f2bf(v.z), f2bf(v.w) };
    reinterpret_cast<ushort4*>(cbw + row * N_IN)[lane] = pk;
    for (int off = 32; off > 0; off >>= 1) ss += __shfl_down(ss, off, 64);
    if (lane == 0) csq[row] = ss;
    if (b < 8) {                      // beta scale: 8 blocks x 256 = 2048
      const int i = b * 256 + tid;
      nb2[i] = -LOG2E * beta[i];
    }
  } else {                            // W: flat float4 -> bf16x4
    const int f = (b - 512) * 256 + tid;   // 73728 float4 total, exact
    float4 v = reinterpret_cast<const float4*>(W)[f];
    ushort4 pk = { f2bf(v.x), f2bf(v.y), f2bf(v.z), f2bf(v.w) };
    reinterpret_cast<ushort4*>(wbw)[f] = pk;
  }
}

// ---------------- fused main kernel: barrier-free steady state ----------------
// 256 WGs x 512 thr (8 waves), 64 rows/WG. Wave = (mw: 32-row half) x (nw: K-slice).
// No LDS staging of B operands: cross-GEMM center fragments and feats W fragments
// are loaded straight from L2-resident bf16 arrays (16 B/lane). A (X rows) lives
// in registers. Each wave owns a PRIVATE R transpose tile (D-layout -> A-layout),
// so the 16-iteration main loop has ZERO __syncthreads -- only intra-wave lgkmcnt.
// Each wave accumulates all 128 outs for its own 32-center (nw) K-slice; the four
// nw-partials merge once at the end via LDS atomicAdd.
__global__ __launch_bounds__(512, 2) void rbfn_main(
    const float* __restrict__ X, const float* __restrict__ bias,
    const unsigned short* __restrict__ cbw,   // [2048][256] bf16
    const unsigned short* __restrict__ wbw,   // [128][2304] bf16
    const float* __restrict__ csq,            // [2048]
    const float* __restrict__ nb2,            // [2048] = -log2e*beta
    float* __restrict__ out)                  // [16384][128] fp32
{
  __shared__ __align__(16) unsigned char pool[36352];
  unsigned short* const Xb = (unsigned short*)pool;          // prologue: 64x264 = 33792 B
  float* const Ob   = (float*)pool;                          // epilogue: 64x128 f32 = 32768 B
  float* const pred = (float*)(pool + 33792);                // 512 f
  float* const xsq  = (float*)(pool + 33792 + 2048);         // 64 f

  const int tid  = threadIdx.x;
  const int wave = tid >> 6;
  const int lane = tid & 63;
  const int l16  = lane & 15;
  const int quad = lane >> 4;
  const int mw   = wave & 1;          // 32-row half
  const int nw   = wave >> 1;         // 0..3: K-slice (X-part kb pair / 32-center slice)
  const int r0   = blockIdx.x * BR;
  // wave-private R tile: 32 rows x 32 centers bf16, stride RTP (2560 B each, in loop phase)
  unsigned short* const Rtw = (unsigned short*)pool + wave * (32 * RTP);

  // --- prologue: stage X tile fp32->bf16 into Xb, |x|^2 partials ---
  {
    const int row = tid >> 3;          // 0..63
    const int q   = tid & 7;
    const float4* gx = reinterpret_cast<const float4*>(X + (r0 + row) * N_IN) + q * 8;
    float ss = 0.f;
#pragma unroll
    for (int j = 0; j < 8; ++j) {
      float4 v = gx[j];
      ss += v.x * v.x + v.y * v.y + v.z * v.z + v.w * v.w;
      ushort4 pk = { f2bf(v.x), f2bf(v.y), f2bf(v.z), f2bf(v.w) };
      *reinterpret_cast<ushort4*>(&Xb[row * XP + q * 32 + j * 4]) = pk;
    }
    pred[tid] = ss;
  }
  __syncthreads();
  if (tid < 64) {
    float s = 0.f;
#pragma unroll
    for (int k = 0; k < 8; ++k) s += pred[tid * 8 + k];
    xsq[tid] = s;
  }
  __syncthreads();                     // xsq visible

  // persistent A fragments: wave's 32 rows x 256 k (64 VGPR)
  bf16x8 areg[2][8];
#pragma unroll
  for (int mt = 0; mt < 2; ++mt)
#pragma unroll
    for (int kb = 0; kb < 8; ++kb)
      areg[mt][kb] = ldfrag(&Xb[(mw * 32 + mt * 16 + l16) * XP + kb * 32 + quad * 8]);

  float xsqr[8];
#pragma unroll
  for (int mt = 0; mt < 2; ++mt)
#pragma unroll
    for (int r = 0; r < 4; ++r)
      xsqr[mt * 4 + r] = xsq[mw * 32 + mt * 16 + quad * 4 + r];
  __syncthreads();                     // Xb/xsq reads done -> Rt region may be written

  f32x4 oacc[2][8] = {};               // 32 rows x 128 outs (this wave's K-partial)

  // === X-part: wave nw covers kb = nw*2, nw*2+1; B-frags direct from global ===
#pragma unroll
  for (int ks = 0; ks < 2; ++ks) {
    const int kb = nw * 2 + ks;
#pragma unroll
    for (int ot = 0; ot < 8; ++ot) {
      bf16x8 bfr = ldfrag(wbw + (ot * 16 + l16) * 2304 + kb * 32 + quad * 8);
#pragma unroll
      for (int mt = 0; mt < 2; ++mt)
        oacc[mt][ot] = __builtin_amdgcn_mfma_f32_16x16x32_bf16(
            areg[mt][kb], bfr, oacc[mt][ot], 0, 0, 0);
    }
  }

  // === radial: 16 blocks of 128 centers; wave handles its 32-center slice ===
  for (int rb = 0; rb < 16; ++rb) {
    const int cbase = rb * 128 + nw * 32;

    // cross GEMM: 32 rows x 32 centers, K=256; B-frags direct from global
    f32x4 cacc[2][2] = {};             // [mt][ct]
#pragma unroll
    for (int kb = 0; kb < 8; ++kb)
#pragma unroll
      for (int ct = 0; ct < 2; ++ct) {
        bf16x8 bfr = ldfrag(cbw + (cbase + ct * 16 + l16) * 256 + kb * 32 + quad * 8);
#pragma unroll
        for (int mt = 0; mt < 2; ++mt)
          cacc[mt][ct] = __builtin_amdgcn_mfma_f32_16x16x32_bf16(
              areg[mt][kb], bfr, cacc[mt][ct], 0, 0, 0);
      }

    // epilogue -> wave-private Rt (no barrier; intra-wave lgkm only)
#pragma unroll
    for (int ct = 0; ct < 2; ++ct) {
      const int cg = cbase + ct * 16 + l16;
      const float cs = csq[cg];
      const float nb = nb2[cg];
#pragma unroll
      for (int mt = 0; mt < 2; ++mt)
#pragma unroll
        for (int r = 0; r < 4; ++r) {
          const int row = mt * 16 + quad * 4 + r;      // D: row = quad*4 + reg
          float sd = xsqr[mt * 4 + r] + cs - 2.f * cacc[mt][ct][r];
          Rtw[row * RTP + ct * 16 + l16] = f2bf(exp2f(nb * sd));
        }
    }

    // feats GEMM: oacc += R[32r x 32c] @ W[:, slice]^T (K=32, verified intrinsic)
    bf16x8 afr[2];
#pragma unroll
    for (int mt = 0; mt < 2; ++mt)
      afr[mt] = ldfrag(&Rtw[(mt * 16 + l16) * RTP + quad * 8]);
#pragma unroll
    for (int ot = 0; ot < 8; ++ot) {
      bf16x8 bfr = ldfrag(wbw + (ot * 16 + l16) * 2304 + 256 + cbase + quad * 8);
#pragma unroll
      for (int mt = 0; mt < 2; ++mt)
        oacc[mt][ot] = __builtin_amdgcn_mfma_f32_16x16x32_bf16(
            afr[mt], bfr, oacc[mt][ot], 0, 0, 0);
    }
  }

  // === merge nw-partials: LDS atomicAdd, then bias + store ===
  __syncthreads();                     // Rt dead -> Ob region reuse
#pragma unroll
  for (int j = 0; j < 4; ++j)
    reinterpret_cast<float4*>(Ob)[tid + j * 512] = float4{0.f, 0.f, 0.f, 0.f};
  __syncthreads();
#pragma unroll
  for (int mt = 0; mt < 2; ++mt)
#pragma unroll
    for (int ot = 0; ot < 8; ++ot)
#pragma unroll
      for (int r = 0; r < 4; ++r) {
        const int row = mw * 32 + mt * 16 + quad * 4 + r;
        atomicAdd(&Ob[row * NOUT + ot * 16 + l16], oacc[mt][ot][r]);
      }
  __syncthreads();
#pragma unroll
  for (int j = 0; j < 4; ++j) {
    const int i4  = tid + j * 512;     // 2048 float4 = 64 rows x 32 col-quads
    const int row = i4 >> 5;
    const int oc4 = i4 & 31;
    float4 v  = reinterpret_cast<float4*>(Ob)[i4];
    float4 bv = reinterpret_cast<const float4*>(bias)[oc4];
    v.x += bv.x; v.y += bv.y; v.z += bv.z; v.w += bv.w;
    reinterpret_cast<float4*>(out + (r0 + row) * NOUT)[oc4] = v;
  }
}

extern "C" void kernel_launch(void* const* d_in, const int* in_sizes, int n_in,
                              void* d_out, int out_size, void* d_ws, size_t ws_size,
                              hipStream_t stream) {
  const float* X       = (const float*)d_in[0];   // [16384,256]
  const float* centers = (const float*)d_in[1];   // [2048,256]
  const float* beta    = (const float*)d_in[2];   // [1,2048]
  const float* W       = (const float*)d_in[3];   // [128,2304]
  const float* bias    = (const float*)d_in[4];   // [128]
  float* out = (float*)d_out;

  char* ws = (char*)d_ws;
  unsigned short* cbw = (unsigned short*)ws;                       // 1,048,576 B
  unsigned short* wbw = (unsigned short*)(ws + 1048576);           //   589,824 B
  float*          csq = (float*)(ws + 1048576 + 589824);           //     8,192 B
  float*          nb2 = (float*)(ws + 1048576 + 589824 + 8192);    //     8,192 B

  rbfn_prep<<<800, 256, 0, stream>>>(centers, W, beta, cbw, wbw, csq, nb2);
  rbfn_main<<<256, 512, 0, stream>>>(X, bias, cbw, wbw, csq, nb2, out);
}